// Round 5
// baseline (291.167 us; speedup 1.0000x reference)
//
#include <hip/hip_runtime.h>
#include <cstdint>

#define B_   2
#define L_   2048
#define D_   512
#define H_   8
#define DH_  64
#define DFC_ 2048

typedef unsigned short ushort_t;
typedef __attribute__((ext_vector_type(8))) short bf16x8;
typedef __attribute__((ext_vector_type(4))) short bf16x4;
typedef __attribute__((ext_vector_type(4))) float f32x4;

#define MFMA32(A, Bv, C) __builtin_amdgcn_mfma_f32_16x16x32_bf16(A, Bv, C, 0, 0, 0)
#define MFMA16(A, Bv, C) __builtin_amdgcn_mfma_f32_16x16x16bf16_1k(A, Bv, C, 0, 0, 0)

__device__ __forceinline__ ushort_t f32_bf16(float f) {
  unsigned u = __float_as_uint(f);
  u += 0x7FFFu + ((u >> 16) & 1u);   // round-to-nearest-even
  return (ushort_t)(u >> 16);
}

__device__ __forceinline__ void gl_lds16(const ushort_t* g, ushort_t* l) {
  __builtin_amdgcn_global_load_lds(
      (const __attribute__((address_space(1))) void*)(const void*)g,
      (__attribute__((address_space(3))) void*)l, 16, 0, 0);
}

// ---------------------------------------------------------------------------
// pack x (2M f32) and rel (1M f32) to bf16 in one launch. grid 1536.
// ---------------------------------------------------------------------------
__global__ __launch_bounds__(256)
void pack_x_rel(const float* __restrict__ x, const float* __restrict__ rel,
                ushort_t* __restrict__ xb, ushort_t* __restrict__ relb) {
  const int bid = blockIdx.x;
  const float* in = (bid < 1024) ? x : rel;
  ushort_t* out = (bid < 1024) ? xb : relb;
  const int base = (bid < 1024) ? bid : (bid - 1024);
  int i = (base * 256 + threadIdx.x) * 8;
  float4 a = *(const float4*)(in + i);
  float4 b = *(const float4*)(in + i + 4);
  union { bf16x8 v; ushort_t s[8]; } u;
  u.s[0] = f32_bf16(a.x); u.s[1] = f32_bf16(a.y);
  u.s[2] = f32_bf16(a.z); u.s[3] = f32_bf16(a.w);
  u.s[4] = f32_bf16(b.x); u.s[5] = f32_bf16(b.y);
  u.s[6] = f32_bf16(b.z); u.s[7] = f32_bf16(b.w);
  *(bf16x8*)(out + i) = u.v;
}

// ---------------------------------------------------------------------------
// All weight transposes in ONE launch. grid 704 blocks.
// ids [0,192): wq/wk/wv (512,512); [192,448): w1 (512,2048); [448,704): w2.
// ---------------------------------------------------------------------------
__global__ __launch_bounds__(256)
void packT_all(const float* __restrict__ wq, const float* __restrict__ wk,
               const float* __restrict__ wv, const float* __restrict__ w1,
               const float* __restrict__ w2, ushort_t* __restrict__ wqkvT,
               ushort_t* __restrict__ w1T, ushort_t* __restrict__ w2T) {
  __shared__ float T[64 * 65];
  const int id = blockIdx.x;
  const float* in; ushort_t* out; int K, N, bx, by;
  if (id < 192) {
    int z = id >> 6, r = id & 63;
    in = (z == 0) ? wq : (z == 1) ? wk : wv;
    out = wqkvT + (size_t)z * 512 * 512;
    K = 512; N = 512; bx = r & 7; by = r >> 3;
  } else if (id < 448) {
    int r = id - 192;
    in = w1; out = w1T; K = 512; N = 2048; bx = r & 31; by = r >> 5;
  } else {
    int r = id - 448;
    in = w2; out = w2T; K = 2048; N = 512; bx = r & 7; by = r >> 3;
  }
  const int t = threadIdx.x;
  const int n0 = bx * 64, k0 = by * 64;
  {
    const int kr = t >> 2, c0 = (t & 3) * 16;
    const float* src = in + (size_t)(k0 + kr) * N + n0 + c0;
#pragma unroll
    for (int u = 0; u < 4; ++u) {
      float4 f = *(const float4*)(src + u * 4);
      T[kr * 65 + c0 + u * 4 + 0] = f.x;
      T[kr * 65 + c0 + u * 4 + 1] = f.y;
      T[kr * 65 + c0 + u * 4 + 2] = f.z;
      T[kr * 65 + c0 + u * 4 + 3] = f.w;
    }
  }
  __syncthreads();
  const int nr = t >> 2, kc0 = (t & 3) * 16;
  union { bf16x8 v; ushort_t s[8]; } o0, o1;
#pragma unroll
  for (int j = 0; j < 8; ++j) {
    o0.s[j] = f32_bf16(T[(kc0 + j) * 65 + nr]);
    o1.s[j] = f32_bf16(T[(kc0 + 8 + j) * 65 + nr]);
  }
  ushort_t* dst = out + (size_t)(n0 + nr) * K + k0 + kc0;
  *(bf16x8*)dst = o0.v;
  *(bf16x8*)(dst + 8) = o1.v;
}

// ---------------------------------------------------------------------------
// MFMA GEMM: C = A(M,K) @ Bt(N,K)^T. 128x128 tile, BK=32, 4 waves.
// MODE 0: f32 raw partial (split-K via blockIdx.z)
// MODE 1: bf16 out +bias +relu
// MODE 2: QKV scatter: q bf16 (B,H,L,DH) pre-scaled 0.125; k same; v -> (B,H,DH,L)
// ---------------------------------------------------------------------------
template <int MODE>
__global__ __launch_bounds__(256, 2)
void gemm_mfma(const ushort_t* __restrict__ A, const ushort_t* __restrict__ Bt,
               const float* __restrict__ b0p, const float* __restrict__ b1p,
               const float* __restrict__ b2p,
               void* __restrict__ out0, void* __restrict__ out1, void* __restrict__ out2,
               int M, int N, int K, int ksplit) {
  __shared__ ushort_t As[128 * 32];
  __shared__ ushort_t Bs[128 * 32];

  const int t  = threadIdx.x;
  const int wv = t >> 6, ln = t & 63;
  const int l16 = ln & 15, lg = ln >> 4;
  const int n0 = blockIdx.x * 128, m0 = blockIdx.y * 128;
  const int mw = (wv >> 1) * 64, nw = (wv & 1) * 64;

  const int kchunk = K / ksplit;
  const int kbeg = blockIdx.z * kchunk, kend = kbeg + kchunk;

  f32x4 acc[4][4] = {};

  for (int k0 = kbeg; k0 < kend; k0 += 32) {
    __syncthreads();
#pragma unroll
    for (int i = 0; i < 2; ++i) {
      const int s = (i * 4 + wv) * 64 + ln;
      const int row = s >> 2, cs = s & 3;
      const int g = cs ^ ((row >> 1) & 3);
      gl_lds16(A + (size_t)(m0 + row) * K + k0 + g * 8, &As[(i * 4 + wv) * 512]);
      gl_lds16(Bt + (size_t)(n0 + row) * K + k0 + g * 8, &Bs[(i * 4 + wv) * 512]);
    }
    __syncthreads();

    bf16x8 af[4], bfr[4];
#pragma unroll
    for (int mi = 0; mi < 4; ++mi) {
      const int ri = mw + mi * 16 + l16;
      af[mi] = *(const bf16x8*)&As[ri * 32 + ((lg ^ ((ri >> 1) & 3)) * 8)];
    }
#pragma unroll
    for (int ni = 0; ni < 4; ++ni) {
      const int rj = nw + ni * 16 + l16;
      bfr[ni] = *(const bf16x8*)&Bs[rj * 32 + ((lg ^ ((rj >> 1) & 3)) * 8)];
    }
#pragma unroll
    for (int mi = 0; mi < 4; ++mi)
#pragma unroll
      for (int ni = 0; ni < 4; ++ni)
        acc[mi][ni] = MFMA32(af[mi], bfr[ni], acc[mi][ni]);
  }

  if (MODE == 0) {
    float* outp = (blockIdx.z == 0) ? (float*)out0 : (float*)out1;
#pragma unroll
    for (int mi = 0; mi < 4; ++mi)
#pragma unroll
      for (int reg = 0; reg < 4; ++reg) {
        const int m = m0 + mw + mi * 16 + lg * 4 + reg;
#pragma unroll
        for (int ni = 0; ni < 4; ++ni) {
          const int c = n0 + nw + ni * 16 + l16;
          outp[(size_t)m * N + c] = acc[mi][ni][reg];
        }
      }
  } else if (MODE == 1) {
    ushort_t* outp = (ushort_t*)out0;
#pragma unroll
    for (int mi = 0; mi < 4; ++mi)
#pragma unroll
      for (int reg = 0; reg < 4; ++reg) {
        const int m = m0 + mw + mi * 16 + lg * 4 + reg;
#pragma unroll
        for (int ni = 0; ni < 4; ++ni) {
          const int c = n0 + nw + ni * 16 + l16;
          float v = acc[mi][ni][reg] + b0p[c];
          outp[(size_t)m * N + c] = f32_bf16(fmaxf(v, 0.f));
        }
      }
  } else {
#pragma unroll
    for (int mi = 0; mi < 4; ++mi)
#pragma unroll
      for (int reg = 0; reg < 4; ++reg) {
        const int m = m0 + mw + mi * 16 + lg * 4 + reg;
        const int b = m >> 11, l = m & (L_ - 1);
#pragma unroll
        for (int ni = 0; ni < 4; ++ni) {
          const int c = n0 + nw + ni * 16 + l16;
          const int which = c >> 9, cc = c & 511;
          const int h = cc >> 6, dh = cc & 63;
          const float* bias = (which == 0) ? b0p : (which == 1) ? b1p : b2p;
          float v = acc[mi][ni][reg] + bias[cc];
          if (which == 0) {
            ((ushort_t*)out0)[(((size_t)b * H_ + h) * L_ + l) * DH_ + dh] =
                f32_bf16(v * 0.125f);                    // q pre-scaled
          } else if (which == 1) {
            ((ushort_t*)out1)[(((size_t)b * H_ + h) * L_ + l) * DH_ + dh] = f32_bf16(v);
          } else {
            ((ushort_t*)out2)[(((size_t)b * H_ + h) * DH_ + dh) * L_ + l] = f32_bf16(v);
          }
        }
      }
  }
}

// ---------------------------------------------------------------------------
// FFN2 split-K combine: out = out + p1 + bias
// ---------------------------------------------------------------------------
__global__ __launch_bounds__(256)
void ffn2_add(float* __restrict__ out, const float* __restrict__ p1,
              const float* __restrict__ bias) {
  int i = (blockIdx.x * 256 + threadIdx.x) * 4;
  float4 a = *(const float4*)(out + i);
  float4 b = *(const float4*)(p1 + i);
  float4 bb = *(const float4*)(bias + (i & (D_ - 1)));
  a.x += b.x + bb.x; a.y += b.y + bb.y;
  a.z += b.z + bb.z; a.w += b.w + bb.w;
  *(float4*)(out + i) = a;
}

// ---------------------------------------------------------------------------
// Barrier-free MFMA flash attention, S^T formulation + KV-split.
// Grid (16 bh, 32 qtile, 2 z). Block = 4 waves; wave w owns q-rows [16w,+16).
// S^T = K@Q^T via x32 MFMA -> C-layout (lane=i, quad*4+reg=j) == A-layout of
// the K=16 MFMA, so P stays in REGISTERS; PV via 16 x16-MFMAs, V^T b64 frags
// direct from global. Skew ring Rc: f32, row=qrow(16/wave), 128 cols + 4-col
// wrap pad; gather = 4 consecutive f32 per lane. No-max softmax; partial
// (unnormalized O, l) per z-block added linearly by attn_combine.
// ---------------------------------------------------------------------------
__global__ __launch_bounds__(256, 4)
void attn_mfma(const ushort_t* __restrict__ q16, const ushort_t* __restrict__ k16,
               const ushort_t* __restrict__ vT, const ushort_t* __restrict__ relb,
               float* __restrict__ Opart, float* __restrict__ Lpart) {
  __shared__ float Rc[64 * 136];   // [qrow][col]; cols 0..127 ring, 128..131 pad

  const int t   = threadIdx.x;
  const int wv  = t >> 6;
  const int ln  = t & 63;
  const int l16 = ln & 15;
  const int lg  = ln >> 4;
  const int bh  = blockIdx.x;
  const int yy  = blockIdx.y;
  const int qb  = (yy < 16) ? yy : (47 - yy);
  const int z   = blockIdx.z;
  const int i0  = qb * 64;
  const int mid = (qb + 2) >> 1;
  const int kbeg = z ? mid : 0;
  const int kend = z ? (qb + 1) : mid;

  const ushort_t* qh = q16 + (size_t)bh * L_ * DH_;
  const ushort_t* kh = k16 + (size_t)bh * L_ * DH_;
  const ushort_t* vh = vT + (size_t)bh * DH_ * L_;
  const ushort_t* relh = relb + (bh & 7) * DH_;

  // Q frags (B-operand: n = lane&15 = qrow; q pre-scaled 0.125)
  bf16x8 qf0, qf1;
  {
    const ushort_t* qrow = qh + (size_t)(i0 + wv * 16 + l16) * DH_ + lg * 8;
    qf0 = *(const bf16x8*)(qrow);
    qf1 = *(const bf16x8*)(qrow + 32);
  }

  const f32x4 zf = {0.f, 0.f, 0.f, 0.f};
  f32x4 Of[4] = {zf, zf, zf, zf};     // O: lane&15=dh, quad*4+reg=i
  float lsum = 0.f;                   // all of this lane's p's are row i=l16

  const int rrow = (wv * 16 + l16) * 136;
  const int r64i = wv * 16 + l16;     // this lane's q-row within the 64-tile

  // QE chunk t (64 e-rows from ep) -> ring slot; D[m=c][n=qrow]
  auto compute_R = [&](const ushort_t* ep, int slotbase) {
#pragma unroll
    for (int cb = 0; cb < 4; ++cb) {
      const ushort_t* e = ep + (size_t)(cb * 16 + l16) * D_ + lg * 8;
      bf16x8 e0 = *(const bf16x8*)(e);
      bf16x8 e1 = *(const bf16x8*)(e + 32);
      f32x4 r = MFMA32(e0, qf0, zf);
      r = MFMA32(e1, qf1, r);
      *(f32x4*)&Rc[rrow + slotbase + cb * 16 + lg * 4] = r;
      if (slotbase == 0 && cb == 0 && lg == 0)
        *(f32x4*)&Rc[rrow + 128] = r;   // wrap pad = ring cols 0..3
    }
  };

  if (kbeg < kend) {
    compute_R(relh + (size_t)(L_ - 64 - i0 + kbeg * 64) * D_, (kbeg & 1) * 64);

    for (int kb = kbeg; kb < kend; ++kb) {
      const int j0 = kb * 64;
      if (kb < qb)
        compute_R(relh + (size_t)(L_ - 64 - i0 + (kb + 1) * 64) * D_,
                  ((kb + 1) & 1) * 64);

      // S^T = K @ Q^T (A = K-frag m=j, B = Q-frag n=i)
      f32x4 sf[4];
#pragma unroll
      for (int cb = 0; cb < 4; ++cb) {
        const ushort_t* kp = kh + (size_t)(j0 + cb * 16 + l16) * DH_ + lg * 8;
        bf16x8 k0 = *(const bf16x8*)(kp);
        bf16x8 k1 = *(const bf16x8*)(kp + 32);
        f32x4 s = MFMA32(k0, qf0, zf);
        sf[cb] = MFMA32(k1, qf1, s);
      }

      // skew-gather (4 consecutive ring cols) + mask + exp + pack to bf16
      const bool diag = (kb == qb);
      bf16x4 pa[4];
#pragma unroll
      for (int cb = 0; cb < 4; ++cb) {
        const int jj0 = cb * 16 + lg * 4;
        const int base = (j0 + jj0 + 63 - r64i) & 127;
        union { bf16x4 v; ushort_t s[4]; } pk;
#pragma unroll
        for (int reg = 0; reg < 4; ++reg) {
          float x = sf[cb][reg] + Rc[rrow + base + reg];
          if (diag && (jj0 + reg) > r64i) x = -1e30f;
          float p = __expf(x);
          lsum += p;
          pk.s[reg] = f32_bf16(p);
        }
        pa[cb] = pk.v;
      }

      // O += P @ V : A = P^T regs (m=i, k=j quad), B = V^T b64 frags (n=dh)
#pragma unroll
      for (int cbp = 0; cbp < 4; ++cbp) {
        const ushort_t* vp = vh + (size_t)(cbp * 16 + l16) * L_ + j0 + lg * 4;
#pragma unroll
        for (int c = 0; c < 4; ++c) {
          bf16x4 vf = *(const bf16x4*)(vp + c * 16);
          Of[cbp] = MFMA16(pa[c], vf, Of[cbp]);
        }
      }
    }
  }

  // epilogue: unnormalized partials
  float tot = lsum;
  tot += __shfl_xor(tot, 16);
  tot += __shfl_xor(tot, 32);
  if (ln < 16 && wv == (t >> 6))   // lanes 0..15 of each wave
    ;
  if (ln < 16)
    Lpart[((size_t)(z * 16 + bh)) * L_ + i0 + wv * 16 + ln] = tot;
#pragma unroll
  for (int reg = 0; reg < 4; ++reg) {
    const int i = i0 + wv * 16 + lg * 4 + reg;
    float* orow = Opart + (((size_t)(z * 16 + bh)) * L_ + i) * DH_;
#pragma unroll
    for (int cbp = 0; cbp < 4; ++cbp)
      orow[cbp * 16 + l16] = Of[cbp][reg];
  }
}

// ---------------------------------------------------------------------------
// attn partial combine: attnb = (O0 + O1) / (l0 + l1), bf16 (B,L,D). grid 2048.
// ---------------------------------------------------------------------------
__global__ __launch_bounds__(256)
void attn_combine(const float* __restrict__ Opart, const float* __restrict__ Lpart,
                  ushort_t* __restrict__ attnb) {
  const int g = blockIdx.x * 256 + threadIdx.x;
  const int dh4 = g & 15, i = (g >> 4) & (L_ - 1), bh = g >> 15;
  const size_t o0 = (((size_t)bh * L_ + i) * DH_) + dh4 * 4;
  const size_t zstride = (size_t)16 * L_ * DH_;
  float4 a = *(const float4*)(Opart + o0);
  float4 b = *(const float4*)(Opart + o0 + zstride);
  const float l = Lpart[(size_t)bh * L_ + i] + Lpart[(size_t)(16 + bh) * L_ + i];
  const float inv = 1.f / l;
  ushort4 o;
  o.x = f32_bf16((a.x + b.x) * inv);
  o.y = f32_bf16((a.y + b.y) * inv);
  o.z = f32_bf16((a.z + b.z) * inv);
  o.w = f32_bf16((a.w + b.w) * inv);
  const int bb = bh >> 3, h = bh & 7;
  *(ushort4*)(attnb + ((size_t)(bb * L_ + i)) * D_ + h * DH_ + dh4 * 4) = o;
}

// ---------------------------------------------------------------------------
extern "C" void kernel_launch(void* const* d_in, const int* in_sizes, int n_in,
                              void* d_out, int out_size, void* d_ws, size_t ws_size,
                              hipStream_t stream) {
  const float* x   = (const float*)d_in[0];
  const float* wq  = (const float*)d_in[2];
  const float* bq  = (const float*)d_in[3];
  const float* wk  = (const float*)d_in[4];
  const float* bk  = (const float*)d_in[5];
  const float* wv  = (const float*)d_in[6];
  const float* bv  = (const float*)d_in[7];
  const float* rel = (const float*)d_in[8];
  const float* w1  = (const float*)d_in[9];
  const float* b1  = (const float*)d_in[10];
  const float* w2  = (const float*)d_in[11];
  const float* b2  = (const float*)d_in[12];

  char* wsb = (char*)d_ws;
  const size_t MB = 1u << 20;
  ushort_t* xb     = (ushort_t*)(wsb + 0 * MB);    // 4 MB; dead after QKV
  ushort_t* attnb  = (ushort_t*)(wsb + 0 * MB);    // 4 MB; aliases xb
  ushort_t* wqkvT  = (ushort_t*)(wsb + 4 * MB);    // 1.5 MB
  ushort_t* w1T    = (ushort_t*)(wsb + 6 * MB);    // 2 MB
  ushort_t* w2T    = (ushort_t*)(wsb + 8 * MB);    // 2 MB
  ushort_t* relb   = (ushort_t*)(wsb + 10 * MB);   // 2 MB
  ushort_t* q16    = (ushort_t*)(wsb + 12 * MB);   // 4 MB (B,H,L,DH)
  ushort_t* k16    = (ushort_t*)(wsb + 16 * MB);   // 4 MB
  ushort_t* vTb    = (ushort_t*)(wsb + 20 * MB);   // 4 MB (B,H,DH,L)
  float*    Opart  = (float*)(wsb + 24 * MB);      // 16 MB (2,16,L,DH) f32
  float*    Lpart  = (float*)(wsb + 40 * MB);      // 256 KB (2,16,L) f32
  ushort_t* hidb   = (ushort_t*)(wsb + 24 * MB);   // 16 MB; clobbers dead Opart
  float*    p1     = (float*)(wsb + 12 * MB);      // 8 MB; clobbers dead q16/k16
  float*    out    = (float*)d_out;

  dim3 blk(256);
  pack_x_rel<<<dim3(1536), blk, 0, stream>>>(x, rel, xb, relb);
  packT_all<<<dim3(704), blk, 0, stream>>>(wq, wk, wv, w1, w2, wqkvT, w1T, w2T);
  // fused QKV projection; emits q (scaled), k, and v already transposed
  gemm_mfma<2><<<dim3(12, 32), blk, 0, stream>>>(
      xb, wqkvT, bq, bk, bv, q16, k16, vTb, B_ * L_, 1536, D_, 1);
  attn_mfma<<<dim3(16, 32, 2), blk, 0, stream>>>(q16, k16, vTb, relb, Opart, Lpart);
  attn_combine<<<dim3(2048), blk, 0, stream>>>(Opart, Lpart, attnb);
  gemm_mfma<1><<<dim3(16, 32), blk, 0, stream>>>(
      attnb, w1T, b1, nullptr, nullptr, hidb, nullptr, nullptr,
      B_ * L_, DFC_, D_, 1);
  gemm_mfma<0><<<dim3(4, 32, 2), blk, 0, stream>>>(
      hidb, w2T, nullptr, nullptr, nullptr, out, p1, nullptr,
      B_ * L_, D_, DFC_, 2);
  ffn2_add<<<dim3(2048), blk, 0, stream>>>(out, p1, b2);
}

// Round 6
// 232.880 us; speedup vs baseline: 1.2503x; 1.2503x over previous
//
#include <hip/hip_runtime.h>
#include <cstdint>

#define B_   2
#define L_   2048
#define D_   512
#define H_   8
#define DH_  64
#define DFC_ 2048

typedef unsigned short ushort_t;
typedef __attribute__((ext_vector_type(8))) short bf16x8;
typedef __attribute__((ext_vector_type(4))) short bf16x4;
typedef __attribute__((ext_vector_type(4))) float f32x4;

#define MFMA32(A, Bv, C) __builtin_amdgcn_mfma_f32_16x16x32_bf16(A, Bv, C, 0, 0, 0)
#define MFMA16(A, Bv, C) __builtin_amdgcn_mfma_f32_16x16x16bf16_1k(A, Bv, C, 0, 0, 0)

__device__ __forceinline__ ushort_t f32_bf16(float f) {
  unsigned u = __float_as_uint(f);
  u += 0x7FFFu + ((u >> 16) & 1u);   // round-to-nearest-even
  return (ushort_t)(u >> 16);
}
__device__ __forceinline__ float bf16_f32(ushort_t u) {
  return __uint_as_float(((unsigned)u) << 16);
}

__device__ __forceinline__ void gl_lds16(const ushort_t* g, ushort_t* l) {
  __builtin_amdgcn_global_load_lds(
      (const __attribute__((address_space(1))) void*)(const void*)g,
      (__attribute__((address_space(3))) void*)l, 16, 0, 0);
}

// ---------------------------------------------------------------------------
// pack x (2M f32) and rel (1M f32) to bf16 in one launch. grid 1536.
// ---------------------------------------------------------------------------
__global__ __launch_bounds__(256)
void pack_x_rel(const float* __restrict__ x, const float* __restrict__ rel,
                ushort_t* __restrict__ xb, ushort_t* __restrict__ relb) {
  const int bid = blockIdx.x;
  const float* in = (bid < 1024) ? x : rel;
  ushort_t* out = (bid < 1024) ? xb : relb;
  const int base = (bid < 1024) ? bid : (bid - 1024);
  int i = (base * 256 + threadIdx.x) * 8;
  float4 a = *(const float4*)(in + i);
  float4 b = *(const float4*)(in + i + 4);
  union { bf16x8 v; ushort_t s[8]; } u;
  u.s[0] = f32_bf16(a.x); u.s[1] = f32_bf16(a.y);
  u.s[2] = f32_bf16(a.z); u.s[3] = f32_bf16(a.w);
  u.s[4] = f32_bf16(b.x); u.s[5] = f32_bf16(b.y);
  u.s[6] = f32_bf16(b.z); u.s[7] = f32_bf16(b.w);
  *(bf16x8*)(out + i) = u.v;
}

// ---------------------------------------------------------------------------
// All weight transposes in ONE launch. grid 704 blocks.
// ---------------------------------------------------------------------------
__global__ __launch_bounds__(256)
void packT_all(const float* __restrict__ wq, const float* __restrict__ wk,
               const float* __restrict__ wv, const float* __restrict__ w1,
               const float* __restrict__ w2, ushort_t* __restrict__ wqkvT,
               ushort_t* __restrict__ w1T, ushort_t* __restrict__ w2T) {
  __shared__ float T[64 * 65];
  const int id = blockIdx.x;
  const float* in; ushort_t* out; int K, N, bx, by;
  if (id < 192) {
    int z = id >> 6, r = id & 63;
    in = (z == 0) ? wq : (z == 1) ? wk : wv;
    out = wqkvT + (size_t)z * 512 * 512;
    K = 512; N = 512; bx = r & 7; by = r >> 3;
  } else if (id < 448) {
    int r = id - 192;
    in = w1; out = w1T; K = 512; N = 2048; bx = r & 31; by = r >> 5;
  } else {
    int r = id - 448;
    in = w2; out = w2T; K = 2048; N = 512; bx = r & 7; by = r >> 3;
  }
  const int t = threadIdx.x;
  const int n0 = bx * 64, k0 = by * 64;
  {
    const int kr = t >> 2, c0 = (t & 3) * 16;
    const float* src = in + (size_t)(k0 + kr) * N + n0 + c0;
#pragma unroll
    for (int u = 0; u < 4; ++u) {
      float4 f = *(const float4*)(src + u * 4);
      T[kr * 65 + c0 + u * 4 + 0] = f.x;
      T[kr * 65 + c0 + u * 4 + 1] = f.y;
      T[kr * 65 + c0 + u * 4 + 2] = f.z;
      T[kr * 65 + c0 + u * 4 + 3] = f.w;
    }
  }
  __syncthreads();
  const int nr = t >> 2, kc0 = (t & 3) * 16;
  union { bf16x8 v; ushort_t s[8]; } o0, o1;
#pragma unroll
  for (int j = 0; j < 8; ++j) {
    o0.s[j] = f32_bf16(T[(kc0 + j) * 65 + nr]);
    o1.s[j] = f32_bf16(T[(kc0 + 8 + j) * 65 + nr]);
  }
  ushort_t* dst = out + (size_t)(n0 + nr) * K + k0 + kc0;
  *(bf16x8*)dst = o0.v;
  *(bf16x8*)(dst + 8) = o1.v;
}

// ---------------------------------------------------------------------------
// MFMA GEMM: C = A(M,K) @ Bt(N,K)^T. 128x128 tile, BK=32, 4 waves.
// ---------------------------------------------------------------------------
template <int MODE>
__global__ __launch_bounds__(256, 2)
void gemm_mfma(const ushort_t* __restrict__ A, const ushort_t* __restrict__ Bt,
               const float* __restrict__ b0p, const float* __restrict__ b1p,
               const float* __restrict__ b2p,
               void* __restrict__ out0, void* __restrict__ out1, void* __restrict__ out2,
               int M, int N, int K, int ksplit) {
  __shared__ ushort_t As[128 * 32];
  __shared__ ushort_t Bs[128 * 32];

  const int t  = threadIdx.x;
  const int wv = t >> 6, ln = t & 63;
  const int l16 = ln & 15, lg = ln >> 4;
  const int n0 = blockIdx.x * 128, m0 = blockIdx.y * 128;
  const int mw = (wv >> 1) * 64, nw = (wv & 1) * 64;

  const int kchunk = K / ksplit;
  const int kbeg = blockIdx.z * kchunk, kend = kbeg + kchunk;

  f32x4 acc[4][4] = {};

  for (int k0 = kbeg; k0 < kend; k0 += 32) {
    __syncthreads();
#pragma unroll
    for (int i = 0; i < 2; ++i) {
      const int s = (i * 4 + wv) * 64 + ln;
      const int row = s >> 2, cs = s & 3;
      const int g = cs ^ ((row >> 1) & 3);
      gl_lds16(A + (size_t)(m0 + row) * K + k0 + g * 8, &As[(i * 4 + wv) * 512]);
      gl_lds16(Bt + (size_t)(n0 + row) * K + k0 + g * 8, &Bs[(i * 4 + wv) * 512]);
    }
    __syncthreads();

    bf16x8 af[4], bfr[4];
#pragma unroll
    for (int mi = 0; mi < 4; ++mi) {
      const int ri = mw + mi * 16 + l16;
      af[mi] = *(const bf16x8*)&As[ri * 32 + ((lg ^ ((ri >> 1) & 3)) * 8)];
    }
#pragma unroll
    for (int ni = 0; ni < 4; ++ni) {
      const int rj = nw + ni * 16 + l16;
      bfr[ni] = *(const bf16x8*)&Bs[rj * 32 + ((lg ^ ((rj >> 1) & 3)) * 8)];
    }
#pragma unroll
    for (int mi = 0; mi < 4; ++mi)
#pragma unroll
      for (int ni = 0; ni < 4; ++ni)
        acc[mi][ni] = MFMA32(af[mi], bfr[ni], acc[mi][ni]);
  }

  if (MODE == 0) {
    float* outp = (blockIdx.z == 0) ? (float*)out0 : (float*)out1;
#pragma unroll
    for (int mi = 0; mi < 4; ++mi)
#pragma unroll
      for (int reg = 0; reg < 4; ++reg) {
        const int m = m0 + mw + mi * 16 + lg * 4 + reg;
#pragma unroll
        for (int ni = 0; ni < 4; ++ni) {
          const int c = n0 + nw + ni * 16 + l16;
          outp[(size_t)m * N + c] = acc[mi][ni][reg];
        }
      }
  } else if (MODE == 1) {
    ushort_t* outp = (ushort_t*)out0;
#pragma unroll
    for (int mi = 0; mi < 4; ++mi)
#pragma unroll
      for (int reg = 0; reg < 4; ++reg) {
        const int m = m0 + mw + mi * 16 + lg * 4 + reg;
#pragma unroll
        for (int ni = 0; ni < 4; ++ni) {
          const int c = n0 + nw + ni * 16 + l16;
          float v = acc[mi][ni][reg] + b0p[c];
          outp[(size_t)m * N + c] = f32_bf16(fmaxf(v, 0.f));
        }
      }
  } else {
#pragma unroll
    for (int mi = 0; mi < 4; ++mi)
#pragma unroll
      for (int reg = 0; reg < 4; ++reg) {
        const int m = m0 + mw + mi * 16 + lg * 4 + reg;
        const int b = m >> 11, l = m & (L_ - 1);
#pragma unroll
        for (int ni = 0; ni < 4; ++ni) {
          const int c = n0 + nw + ni * 16 + l16;
          const int which = c >> 9, cc = c & 511;
          const int h = cc >> 6, dh = cc & 63;
          const float* bias = (which == 0) ? b0p : (which == 1) ? b1p : b2p;
          float v = acc[mi][ni][reg] + bias[cc];
          if (which == 0) {
            ((ushort_t*)out0)[(((size_t)b * H_ + h) * L_ + l) * DH_ + dh] =
                f32_bf16(v * 0.125f);                    // q pre-scaled
          } else if (which == 1) {
            ((ushort_t*)out1)[(((size_t)b * H_ + h) * L_ + l) * DH_ + dh] = f32_bf16(v);
          } else {
            ((ushort_t*)out2)[(((size_t)b * H_ + h) * DH_ + dh) * L_ + l] = f32_bf16(v);
          }
        }
      }
  }
}

// ---------------------------------------------------------------------------
// FFN2 split-K combine: out = out + p1 + bias
// ---------------------------------------------------------------------------
__global__ __launch_bounds__(256)
void ffn2_add(float* __restrict__ out, const float* __restrict__ p1,
              const float* __restrict__ bias) {
  int i = (blockIdx.x * 256 + threadIdx.x) * 4;
  float4 a = *(const float4*)(out + i);
  float4 b = *(const float4*)(p1 + i);
  float4 bb = *(const float4*)(bias + (i & (D_ - 1)));
  a.x += b.x + bb.x; a.y += b.y + bb.y;
  a.z += b.z + bb.z; a.w += b.w + bb.w;
  *(float4*)(out + i) = a;
}

// ---------------------------------------------------------------------------
// MFMA flash attention, S^T form, LDS-staged K/V (swizzled global_load_lds),
// bf16 skew ring, P in registers, KV-split z=2. Grid (16 bh, 32 qtile, 2 z).
// Wave w owns q-rows [16w,16w+16); lane l16 = its q-row, lg = j/dh quad.
//  - S^T = K@Q^T (x32 MFMA, A=K frag b128 from LDS, B=Q regs)
//  - ring: QE^T chunks via x32 (A=e direct-global, B=Q) -> bf16 [qrow][col&127]
//  - PV: O^T = V^T@P^T (x16 MFMA, A=V^T b64 frags from LDS, B=P^T regs)
// ---------------------------------------------------------------------------
__global__ __launch_bounds__(256, 4)
void attn_mfma(const ushort_t* __restrict__ q16, const ushort_t* __restrict__ k16,
               const ushort_t* __restrict__ vT, const ushort_t* __restrict__ relb,
               float* __restrict__ Opart, float* __restrict__ Lpart) {
  __shared__ ushort_t Ks[64 * 64];    // [j][dh], 16B chunks swizzled by (j&7)
  __shared__ ushort_t Vs[64 * 64];    // [dh][j], 16B chunks swizzled by (dh&7)
  __shared__ ushort_t Rc[64 * 136];   // ring [qrow][col]; 128 cols + 3 pad

  const int t   = threadIdx.x;
  const int wv  = t >> 6;
  const int ln  = t & 63;
  const int l16 = ln & 15;
  const int lg  = ln >> 4;
  const int bh  = blockIdx.x;
  const int yy  = blockIdx.y;
  const int qb  = (yy < 16) ? yy : (47 - yy);
  const int z   = blockIdx.z;
  const int i0  = qb * 64;
  const int mid = (qb + 2) >> 1;
  const int kbeg = z ? mid : 0;
  const int kend = z ? (qb + 1) : mid;

  const ushort_t* qh = q16 + (size_t)bh * L_ * DH_;
  const ushort_t* kh = k16 + (size_t)bh * L_ * DH_;
  const ushort_t* vh = vT + (size_t)bh * DH_ * L_;
  const ushort_t* relh = relb + (bh & 7) * DH_;

  const int r64i = wv * 16 + l16;     // this lane's q-row within the 64-tile
  const int rrow = r64i * 136;

  // Q frags (B-operand: n=l16 -> q-row r64i; k=dh; q pre-scaled 0.125)
  bf16x8 qf0, qf1;
  {
    const ushort_t* qr = qh + (size_t)(i0 + r64i) * DH_ + lg * 8;
    qf0 = *(const bf16x8*)(qr);
    qf1 = *(const bf16x8*)(qr + 32);
  }

  const f32x4 zf = {0.f, 0.f, 0.f, 0.f};
  f32x4 Of[4] = {zf, zf, zf, zf};     // Of[cb2][reg] = O[i=r64i][dh=cb2*16+lg*4+reg]
  float lsum = 0.f;

  // QE chunk (64 e-rows at mbase) -> ring slot; D[m=ecol][n=qrow=l16]
  auto compute_R = [&](int mbase, int slotbase) {
#pragma unroll
    for (int cb = 0; cb < 4; ++cb) {
      const ushort_t* e = relh + (size_t)(mbase + cb * 16 + l16) * D_ + lg * 8;
      bf16x8 e0 = *(const bf16x8*)(e);
      bf16x8 e1 = *(const bf16x8*)(e + 32);
      f32x4 r = MFMA32(e0, qf0, zf);
      r = MFMA32(e1, qf1, r);
      ushort4 w;
      w.x = f32_bf16(r[0]); w.y = f32_bf16(r[1]);
      w.z = f32_bf16(r[2]); w.w = f32_bf16(r[3]);
      *(ushort4*)&Rc[rrow + slotbase + cb * 16 + lg * 4] = w;
      if (slotbase == 0 && cb == 0 && lg == 0)
        *(ushort4*)&Rc[rrow + 128] = w;   // pad cols 128..131 = ring cols 0..3
    }
  };

  if (kbeg < kend) {
    compute_R(L_ - 64 - i0 + kbeg * 64, (kbeg & 1) * 64);

    for (int kb = kbeg; kb < kend; ++kb) {
      const int j0 = kb * 64;
      __syncthreads();   // all waves done reading prior Ks/Vs
      // stage K tile [j][dh] and V^T tile [dh][j], 16B-chunk swizzle on source
#pragma unroll
      for (int i = 0; i < 2; ++i) {
        const int s = (i * 4 + wv) * 64 + ln;
        const int row = s >> 3, c = s & 7;
        const int g = c ^ (row & 7);
        gl_lds16(kh + (size_t)(j0 + row) * DH_ + g * 8, &Ks[(i * 4 + wv) * 512]);
        gl_lds16(vh + (size_t)row * L_ + j0 + g * 8, &Vs[(i * 4 + wv) * 512]);
      }
      // ring chunk kb+1 overlaps the DMA (global e reads on TA pipe)
      if (kb < qb)
        compute_R(L_ - 64 - i0 + (kb + 1) * 64, ((kb + 1) & 1) * 64);
      __syncthreads();

      // S^T = K @ Q^T
      f32x4 sf[4];
#pragma unroll
      for (int cb = 0; cb < 4; ++cb) {
        const int j = cb * 16 + l16;
        const int sw = j & 7;
        bf16x8 k0 = *(const bf16x8*)&Ks[j * 64 + ((lg ^ sw) * 8)];
        bf16x8 k1 = *(const bf16x8*)&Ks[j * 64 + (((lg + 4) ^ sw) * 8)];
        f32x4 s = MFMA32(k0, qf0, zf);
        sf[cb] = MFMA32(k1, qf1, s);
      }

      // skew-gather + mask + exp; P^T packed to bf16 regs
      const bool diag = (kb == qb);
      bf16x4 pa[4];
#pragma unroll
      for (int cb = 0; cb < 4; ++cb) {
        const int jj0 = cb * 16 + lg * 4;
        const int base = (j0 + jj0 + 63 - r64i) & 127;
        union { bf16x4 v; ushort_t s[4]; } pk;
#pragma unroll
        for (int reg = 0; reg < 4; ++reg) {
          float x = sf[cb][reg] + bf16_f32(Rc[rrow + base + reg]);
          if (diag && (jj0 + reg) > r64i) x = -1e30f;
          float p = __expf(x);
          lsum += p;
          pk.s[reg] = f32_bf16(p);
        }
        pa[cb] = pk.v;
      }

      // O^T += V^T @ P^T (x16 MFMA; A=V^T frag, B=P^T regs)
#pragma unroll
      for (int cb2 = 0; cb2 < 4; ++cb2) {
        const int dh = cb2 * 16 + l16;
        const int sw = dh & 7;
        const ushort_t* vrow = &Vs[dh * 64];
#pragma unroll
        for (int cb = 0; cb < 4; ++cb) {
          const int cc = cb * 2 + (lg >> 1);
          bf16x4 vf = *(const bf16x4*)&vrow[((cc ^ sw) * 8) + (lg & 1) * 4];
          Of[cb2] = MFMA16(vf, pa[cb], Of[cb2]);
        }
      }
    }
  }

  // epilogue: unnormalized partials; lsum reduce over lg groups (same q-row)
  float tot = lsum;
  tot += __shfl_xor(tot, 16);
  tot += __shfl_xor(tot, 32);
  if (lg == 0)
    Lpart[((size_t)(z * 16 + bh)) * L_ + i0 + r64i] = tot;
  float* orow = Opart + (((size_t)(z * 16 + bh)) * L_ + i0 + r64i) * DH_;
#pragma unroll
  for (int cb2 = 0; cb2 < 4; ++cb2)
    *(f32x4*)&orow[cb2 * 16 + lg * 4] = Of[cb2];
}

// ---------------------------------------------------------------------------
// attn partial combine: attnb = (O0 + O1) / (l0 + l1), bf16 (B,L,D). grid 2048.
// ---------------------------------------------------------------------------
__global__ __launch_bounds__(256)
void attn_combine(const float* __restrict__ Opart, const float* __restrict__ Lpart,
                  ushort_t* __restrict__ attnb) {
  const int g = blockIdx.x * 256 + threadIdx.x;
  const int dh4 = g & 15, i = (g >> 4) & (L_ - 1), bh = g >> 15;
  const size_t o0 = (((size_t)bh * L_ + i) * DH_) + dh4 * 4;
  const size_t zstride = (size_t)16 * L_ * DH_;
  float4 a = *(const float4*)(Opart + o0);
  float4 b = *(const float4*)(Opart + o0 + zstride);
  const float l = Lpart[(size_t)bh * L_ + i] + Lpart[(size_t)(16 + bh) * L_ + i];
  const float inv = 1.f / l;
  ushort4 o;
  o.x = f32_bf16((a.x + b.x) * inv);
  o.y = f32_bf16((a.y + b.y) * inv);
  o.z = f32_bf16((a.z + b.z) * inv);
  o.w = f32_bf16((a.w + b.w) * inv);
  const int bb = bh >> 3, h = bh & 7;
  *(ushort4*)(attnb + ((size_t)(bb * L_ + i)) * D_ + h * DH_ + dh4 * 4) = o;
}

// ---------------------------------------------------------------------------
extern "C" void kernel_launch(void* const* d_in, const int* in_sizes, int n_in,
                              void* d_out, int out_size, void* d_ws, size_t ws_size,
                              hipStream_t stream) {
  const float* x   = (const float*)d_in[0];
  const float* wq  = (const float*)d_in[2];
  const float* bq  = (const float*)d_in[3];
  const float* wk  = (const float*)d_in[4];
  const float* bk  = (const float*)d_in[5];
  const float* wv  = (const float*)d_in[6];
  const float* bv  = (const float*)d_in[7];
  const float* rel = (const float*)d_in[8];
  const float* w1  = (const float*)d_in[9];
  const float* b1  = (const float*)d_in[10];
  const float* w2  = (const float*)d_in[11];
  const float* b2  = (const float*)d_in[12];

  char* wsb = (char*)d_ws;
  const size_t MB = 1u << 20;
  ushort_t* xb     = (ushort_t*)(wsb + 0 * MB);    // 4 MB; dead after QKV
  ushort_t* attnb  = (ushort_t*)(wsb + 0 * MB);    // 4 MB; aliases xb
  ushort_t* wqkvT  = (ushort_t*)(wsb + 4 * MB);    // 1.5 MB
  ushort_t* w1T    = (ushort_t*)(wsb + 6 * MB);    // 2 MB
  ushort_t* w2T    = (ushort_t*)(wsb + 8 * MB);    // 2 MB
  ushort_t* relb   = (ushort_t*)(wsb + 10 * MB);   // 2 MB
  ushort_t* q16    = (ushort_t*)(wsb + 12 * MB);   // 4 MB (B,H,L,DH)
  ushort_t* k16    = (ushort_t*)(wsb + 16 * MB);   // 4 MB
  ushort_t* vTb    = (ushort_t*)(wsb + 20 * MB);   // 4 MB (B,H,DH,L)
  float*    Opart  = (float*)(wsb + 24 * MB);      // 16 MB (2,16,L,DH) f32
  float*    Lpart  = (float*)(wsb + 40 * MB);      // 256 KB (2,16,L) f32
  ushort_t* hidb   = (ushort_t*)(wsb + 24 * MB);   // 16 MB; clobbers dead Opart
  float*    p1     = (float*)(wsb + 12 * MB);      // 8 MB; clobbers dead q16/k16
  float*    out    = (float*)d_out;

  dim3 blk(256);
  pack_x_rel<<<dim3(1536), blk, 0, stream>>>(x, rel, xb, relb);
  packT_all<<<dim3(704), blk, 0, stream>>>(wq, wk, wv, w1, w2, wqkvT, w1T, w2T);
  // fused QKV projection; emits q (scaled), k, and v already transposed
  gemm_mfma<2><<<dim3(12, 32), blk, 0, stream>>>(
      xb, wqkvT, bq, bk, bv, q16, k16, vTb, B_ * L_, 1536, D_, 1);
  attn_mfma<<<dim3(16, 32, 2), blk, 0, stream>>>(q16, k16, vTb, relb, Opart, Lpart);
  attn_combine<<<dim3(2048), blk, 0, stream>>>(Opart, Lpart, attnb);
  gemm_mfma<1><<<dim3(16, 32), blk, 0, stream>>>(
      attnb, w1T, b1, nullptr, nullptr, hidb, nullptr, nullptr,
      B_ * L_, DFC_, D_, 1);
  gemm_mfma<0><<<dim3(4, 32, 2), blk, 0, stream>>>(
      hidb, w2T, nullptr, nullptr, nullptr, out, p1, nullptr,
      B_ * L_, D_, DFC_, 2);
  ffn2_add<<<dim3(2048), blk, 0, stream>>>(out, p1, b2);
}